// Round 15
// baseline (100.221 us; speedup 1.0000x reference)
//
#include <hip/hip_runtime.h>

typedef _Float16 half8 __attribute__((ext_vector_type(8)));
typedef _Float16 half4 __attribute__((ext_vector_type(4)));
typedef float f32x4 __attribute__((ext_vector_type(4)));

#define W 512
#define H 512
#define NPIX (16.0f*3.0f*512.0f*512.0f)
#define NACC 64
#define TSTR 84            // TP fast-axis stride (halves): 42-dword lane stride
                           // -> lo*42 mod 32 = 16 distinct banks (conflict-light)
#define TPL (64*TSTR)      // one field plane: 64 outcols x 84 rowidx

#define MFMA(A,B) __builtin_amdgcn_mfma_f32_16x16x32_f16((A),(B),zero4,0,0,0)

// Block = 64 out rows x 64 out cols, 256 threads (4 waves).
// ZERO barriers: wave wv owns out-cols [16wv,16wv+16) end-to-end (H writes and
// V reads the same private TP region -> within-wave lgkmcnt ordering only).
// Grid = 48 planes x 8 sy x 8 sx = 3072 one-shot blocks; 43KB LDS -> 3 blocks/CU.
__global__ __launch_bounds__(256) void ssim_main(const float* __restrict__ pred,
                                                 const float* __restrict__ targ,
                                                 const float* __restrict__ win,
                                                 float* __restrict__ acc) {
    const int tid  = threadIdx.x;
    const int lane = tid & 63;
    const int wv   = tid >> 6;          // wave 0..3 = out col-tile, both passes
    const int lo   = lane & 15;
    const int hi   = lane >> 4;

    __shared__ _Float16 TP[4 * TPL];    // 43008 B: 0:mu1 1:mu2 2:q 3:pt

    // Per-lane band weights straight from global (one cache line, L1-hot):
    // B[n][k] = g[k - n - 3]; n = lo, k = hi*8 + j. No LDS, no barrier.
    const f32x4 zero4 = {0.f, 0.f, 0.f, 0.f};
    const float inv = __builtin_amdgcn_rcpf(sqrtf(win[60]));
    half8 Bw;
    #pragma unroll
    for (int j = 0; j < 8; ++j) {
        const int d = hi * 8 + j - lo - 3;
        float v = 0.f;
        if (d >= 0 && d <= 10) v = win[55 + d] * inv;
        Bw[j] = (_Float16)v;
    }

    // Tile coords with XCD swizzle (3072 % 8 == 0, bijective).
    const int b  = (blockIdx.x & 7) * 384 + (blockIdx.x >> 3);
    const int sx = b & 7, sy = (b >> 3) & 7, nc = b >> 6;
    const int x0 = sx * 64, y0 = sy * 64;
    const float* Pb = pred + (size_t)nc * (W * H);
    const float* Tb = targ + (size_t)nc * (W * H);

    const float C1 = 1e-4f, C2 = 9e-4f;

    // ---- H-pass: 5 private row-tile tasks for this wave's 16 out cols. ----
    // A row m = lo -> image row y0-8+16rt+lo; k = hi*8+j -> image col
    // x0+16wv-8+hi*8+j. D row = hi*4+reg = H-conv'd image row idx, col = lo.
    const int cb0     = x0 + wv * 16 - 8;
    const int cbase   = cb0 + hi * 8;
    const bool colsafe = (cb0 >= 0) && (cb0 + 31 < W);

    #pragma unroll
    for (int rt = 0; rt < 5; ++rt) {
        const int rowbase = y0 - 8 + rt * 16;
        const int row     = rowbase + lo;
        float pf[8], tf[8];
        if (colsafe && rowbase >= 0 && rowbase + 15 < H) {   // wave-uniform
            const float* Pp = Pb + (size_t)row * W + cbase;
            const float* Tp = Tb + (size_t)row * W + cbase;
            *(f32x4*)&pf[0] = *(const f32x4*)Pp;
            *(f32x4*)&pf[4] = *(const f32x4*)(Pp + 4);
            *(f32x4*)&tf[0] = *(const f32x4*)Tp;
            *(f32x4*)&tf[4] = *(const f32x4*)(Tp + 4);
        } else {
            const bool rok = (unsigned)row < H;
            const int  rid = rok ? row : 0;
            #pragma unroll
            for (int j = 0; j < 8; ++j) {
                const int  c  = cbase + j;
                const int  ci = ((unsigned)c < W) ? c : 0;
                const bool ok = rok && ((unsigned)c < W);
                const float pv = Pb[(size_t)rid * W + ci];
                const float tv = Tb[(size_t)rid * W + ci];
                pf[j] = ok ? pv : 0.f;           // zero padding
                tf[j] = ok ? tv : 0.f;
            }
        }
        half8 pa, ta;
        #pragma unroll
        for (int j = 0; j < 8; ++j) {
            pa[j] = (_Float16)pf[j];
            ta[j] = (_Float16)tf[j];
        }
        const half8 qa = pa * pa + ta * ta;      // q = p^2 + t^2 (validated R13/R14)
        const half8 xa = pa * ta;                // x = p*t
        const f32x4 d0 = MFMA(pa, Bw);
        const f32x4 d1 = MFMA(ta, Bw);
        const f32x4 d2 = MFMA(qa, Bw);
        const f32x4 d3 = MFMA(xa, Bw);
        // Transposed store into this wave's private TP cols:
        // TP[outcol = 16wv+lo][rowidx = 16rt + hi*4 + reg].
        const int tb = (wv * 16 + lo) * TSTR + rt * 16 + hi * 4;
        half4 h0, h1, h2, h3;
        #pragma unroll
        for (int r = 0; r < 4; ++r) {
            h0[r] = (_Float16)d0[r]; h1[r] = (_Float16)d1[r];
            h2[r] = (_Float16)d2[r]; h3[r] = (_Float16)d3[r];
        }
        *(half4*)&TP[0 * TPL + tb] = h0;
        *(half4*)&TP[1 * TPL + tb] = h1;
        *(half4*)&TP[2 * TPL + tb] = h2;
        *(half4*)&TP[3 * TPL + tb] = h3;
    }
    // NO barrier: V-pass reads only this wave's own TP region (lgkmcnt RAW).

    // ---- V-pass + SSIM epilogue: 4 private row-tile tasks. ----
    // TP rowidx 77..79 hold finite junk whose band weight is exactly 0 (g idx > 10).
    float sum = 0.f;
    #pragma unroll
    for (int rtv = 0; rtv < 4; ++rtv) {
        const int abase = (wv * 16 + lo) * TSTR + rtv * 16 + hi * 8;
        const half8 a0 = *(const half8*)&TP[0 * TPL + abase];
        const half8 a1 = *(const half8*)&TP[1 * TPL + abase];
        const half8 a2 = *(const half8*)&TP[2 * TPL + abase];
        const half8 a3 = *(const half8*)&TP[3 * TPL + abase];
        const f32x4 m1 = MFMA(a0, Bw);
        const f32x4 m2 = MFMA(a1, Bw);
        const f32x4 qq = MFMA(a2, Bw);
        const f32x4 pt = MFMA(a3, Bw);
        #pragma unroll
        for (int r = 0; r < 4; ++r) {
            const float mu1 = m1[r], mu2 = m2[r];
            const float ms  = fmaf(mu1, mu1, mu2 * mu2);   // mu1^2 + mu2^2
            const float m12 = mu1 * mu2;
            const float s12 = pt[r] - m12;                 // sigma12
            const float ssm = qq[r] - ms;                  // sigma1^2 + sigma2^2
            const float num = fmaf(2.f, m12, C1) * fmaf(2.f, s12, C2);
            const float den = (ms + C1) * (ssm + C2);
            sum += num * __builtin_amdgcn_rcpf(den);
        }
    }

    // ---- Per-wave reduce + per-wave atomic (no block reduce, no barrier). ----
    #pragma unroll
    for (int off = 32; off > 0; off >>= 1) sum += __shfl_down(sum, off, 64);
    if (lane == 0)
        atomicAdd(&acc[(blockIdx.x * 4 + wv) & (NACC - 1)], sum);
}

__global__ void ssim_final(const float* __restrict__ acc, float* __restrict__ out) {
    float s = 0.f;
    #pragma unroll
    for (int i = 0; i < NACC; ++i) s += acc[i];
    out[0] = 0.1f * (1.0f - s / NPIX);
}

extern "C" void kernel_launch(void* const* d_in, const int* in_sizes, int n_in,
                              void* d_out, int out_size, void* d_ws, size_t ws_size,
                              hipStream_t stream) {
    const float* pred = (const float*)d_in[0];
    const float* targ = (const float*)d_in[1];
    const float* win  = (const float*)d_in[2];
    float* out = (float*)d_out;
    float* acc = (float*)d_ws;

    hipMemsetAsync(acc, 0, NACC * sizeof(float), stream);  // fresh accumulators
    ssim_main<<<3072, 256, 0, stream>>>(pred, targ, win, acc);
    ssim_final<<<1, 1, 0, stream>>>(acc, out);
}

// Round 16
// 53.478 us; speedup vs baseline: 1.8741x; 1.8741x over previous
//
#include <hip/hip_runtime.h>

typedef _Float16 half8 __attribute__((ext_vector_type(8)));
typedef _Float16 half4 __attribute__((ext_vector_type(4)));
typedef float f32x4 __attribute__((ext_vector_type(4)));

#define W 512
#define H 512
#define NPIX (16.0f*3.0f*512.0f*512.0f)
#define NACC 64
#define AFL 3696           // float offset of targ inside a stage buffer (924 chunks * 4)
#define SFL 7424           // floats per stage buffer (29 instr * 256)
#define NINST 29           // DMA instructions per tile (1848 chunks + pad)
#define TPSTR 80           // TP rowidx stride (halves); rowidx 77..79 pre-zeroed, never written
#define TPL 2560           // halves per TP plane = 32 outcols * 80
#define NT 12              // tiles per block: 6144 tiles / 512 blocks

#define VMCNT0() asm volatile("s_waitcnt vmcnt(0)" ::: "memory")
#define LGKM0()  asm volatile("s_waitcnt lgkmcnt(0)" ::: "memory")
#define BAR()    { asm volatile("" ::: "memory"); __builtin_amdgcn_s_barrier(); asm volatile("" ::: "memory"); }
#define MFMA(A,B) __builtin_amdgcn_mfma_f32_16x16x32_f16((A),(B),zero4,0,0,0)

// Block = 64 out rows x 32 out cols per tile, 256 threads (4 waves).
// 512 persistent blocks = EXACTLY 2/CU (no tail); LDS 80.0 KB/block.
// Two independent barrier domains per CU: block A's DMA drain overlaps block B's compute.
__global__ __launch_bounds__(256) void ssim_main(const float* __restrict__ pred,
                                                 const float* __restrict__ targ,
                                                 const float* __restrict__ win,
                                                 float* __restrict__ ws) {
    const int tid  = threadIdx.x;
    const int lane = tid & 63;
    const int wv   = tid >> 6;          // wave 0..3
    const int lo   = lane & 15;
    const int hi   = lane >> 4;

    float* acc = ws;                    // 64 accumulator slots
    const float* zp = ws + 64;          // zero page (DMA source for OOB lanes)

    __shared__ float stageA[SFL];       // 29696 B: pred [0,AFL) + targ [AFL,..)
    __shared__ float stageB[SFL];       // 29696 B
    __shared__ _Float16 TP[4 * TPL];    // 20480 B: 0:mu1 1:mu2 2:q 3:pt
    __shared__ _Float16 gw[64];         // 128 B  -> total 80000 B < 81920

    // gw[18+d] = g[d] for d in [0,10], zero elsewhere (g from window row 5).
    if (tid < 64) {
        const int d = tid - 18;
        float val = 0.f;
        if (d >= 0 && d <= 10)
            val = win[55 + d] * __builtin_amdgcn_rcpf(sqrtf(win[60]));
        gw[tid] = (_Float16)val;
    }
    // Pre-zero ALL of TP once (persistent block): rowidx 77..79 stay 0 forever.
    {
        const half4 z4 = {(_Float16)0.f, (_Float16)0.f, (_Float16)0.f, (_Float16)0.f};
        #pragma unroll
        for (int i = 0; i < 10; ++i)
            *(half4*)&TP[(i * 256 + tid) * 4] = z4;
    }

    // Per-slot DMA constants (tile-invariant). Chunk id = inst*64+lane in [0,1848):
    // arr = id>=924; cid = id-924*arr; r = cid/12 (rows 0..76); cc = cid%12.
    // Staged (r,cc) covers image (y0-8+r, x0-8+4cc .. +3).
    int prow[8], pcol[8], parr[8];
    #pragma unroll
    for (int s = 0; s < 8; ++s) {
        const int inst = s * 4 + wv;
        const int id   = inst * 64 + lane;
        const bool okid = (id < 1848);
        const int arr  = (id >= 924 && okid) ? 1 : 0;
        const int cid  = id - 924 * arr;
        const int r    = (cid * 5462) >> 16;   // exact /12 for cid < 1200
        const int cc   = cid - r * 12;
        prow[s] = okid ? r : (1 << 20);        // forces OOB -> zero page
        pcol[s] = cc * 4 - 8;
        parr[s] = arr;
    }

    const f32x4 zero4 = {0.f, 0.f, 0.f, 0.f};
    const float C1 = 1e-4f, C2 = 9e-4f;
    float sum = 0.f;

    // XCD swizzle (512 % 8 == 0, bijective): 64 consecutive blocks per XCD.
    const int bsw = (blockIdx.x & 7) * 64 + (blockIdx.x >> 3);
    const int t0  = bsw * NT;

#define STAGE(tidx, BUF)                                                       \
    {                                                                          \
        const int nc = (tidx) >> 7, rem = (tidx) & 127;                        \
        const int y0 = (rem >> 4) * 64, x0 = (rem & 15) * 32;                  \
        const float* Pb = pred + (size_t)nc * (W * H);                         \
        const float* Tb = targ + (size_t)nc * (W * H);                         \
        _Pragma("unroll")                                                      \
        for (int s = 0; s < 8; ++s) {                                          \
            const int inst = s * 4 + wv;                                       \
            if (inst < NINST) {              /* wave-uniform */                \
                const int gy = y0 - 8 + prow[s];                               \
                const int gx = x0 + pcol[s];                                   \
                const bool ok = ((unsigned)gy < H) && ((unsigned)gx < W);      \
                const float* bp  = parr[s] ? Tb : Pb;                          \
                const float* src = ok ? (bp + ((size_t)gy * W + gx)) : zp;     \
                __builtin_amdgcn_global_load_lds(                              \
                    (const __attribute__((address_space(1))) void*)src,        \
                    (__attribute__((address_space(3))) void*)&BUF[inst * 256], \
                    16, 0, 0);                                                 \
            }                                                                  \
        }                                                                      \
        __builtin_amdgcn_sched_barrier(0);   /* pin DMA issue early */         \
    }

// H-pass: 10 tasks (rt 0..4 x ct 0..1) over 4 waves; masked store keeps
// TP rowidx 77..79 untouched (rt=4 rows 77..79 are junk-but-finite reads).
#define COMPUTE(BUF)                                                           \
    {                                                                          \
        _Pragma("unroll")                                                      \
        for (int it = 0; it < 3; ++it) {                                       \
            const int t = wv + it * 4;                                         \
            if (t < 10) {                    /* wave-uniform */                \
                const int rt = t >> 1, ct = t & 1;                             \
                const float* SP = &BUF[(rt * 16 + lo) * 48 + ct * 16 + hi * 8];\
                float pf[8], tf[8];                                            \
                *(f32x4*)&pf[0] = *(const f32x4*)SP;                           \
                *(f32x4*)&pf[4] = *(const f32x4*)(SP + 4);                     \
                *(f32x4*)&tf[0] = *(const f32x4*)(SP + AFL);                   \
                *(f32x4*)&tf[4] = *(const f32x4*)(SP + AFL + 4);               \
                half8 pa, ta;                                                  \
                _Pragma("unroll")                                              \
                for (int j = 0; j < 8; ++j) {                                  \
                    pa[j] = (_Float16)pf[j];                                   \
                    ta[j] = (_Float16)tf[j];                                   \
                }                                                              \
                const half8 qa = pa * pa + ta * ta;                            \
                const half8 xa = pa * ta;                                      \
                const f32x4 d0 = MFMA(pa, Bw);                                 \
                const f32x4 d1 = MFMA(ta, Bw);                                 \
                const f32x4 d2 = MFMA(qa, Bw);                                 \
                const f32x4 d3 = MFMA(xa, Bw);                                 \
                const int tb = (ct * 16 + lo) * TPSTR + rt * 16 + hi * 4;      \
                if (rt == 4 && hi == 3) {    /* only rowidx 76 is real */      \
                    TP[0 * TPL + tb] = (_Float16)d0[0];                        \
                    TP[1 * TPL + tb] = (_Float16)d1[0];                        \
                    TP[2 * TPL + tb] = (_Float16)d2[0];                        \
                    TP[3 * TPL + tb] = (_Float16)d3[0];                        \
                } else {                                                       \
                    half4 h0, h1, h2, h3;                                      \
                    _Pragma("unroll")                                          \
                    for (int r = 0; r < 4; ++r) {                              \
                        h0[r] = (_Float16)d0[r]; h1[r] = (_Float16)d1[r];      \
                        h2[r] = (_Float16)d2[r]; h3[r] = (_Float16)d3[r];      \
                    }                                                          \
                    *(half4*)&TP[0 * TPL + tb] = h0;                           \
                    *(half4*)&TP[1 * TPL + tb] = h1;                           \
                    *(half4*)&TP[2 * TPL + tb] = h2;                           \
                    *(half4*)&TP[3 * TPL + tb] = h3;                           \
                }                                                              \
            }                                                                  \
        }                                                                      \
        LGKM0(); BAR();                      /* TP complete; DMA still flying */\
        _Pragma("unroll")                                                      \
        for (int iv = 0; iv < 2; ++iv) {                                       \
            const int v = wv + iv * 4;                                         \
            const int rtv = v >> 1, ct = v & 1;                                \
            const int ah = (ct * 16 + lo) * TPSTR + rtv * 16 + hi * 8;         \
            const half8 a0 = *(const half8*)&TP[0 * TPL + ah];                 \
            const half8 a1 = *(const half8*)&TP[1 * TPL + ah];                 \
            const half8 a2 = *(const half8*)&TP[2 * TPL + ah];                 \
            const half8 a3 = *(const half8*)&TP[3 * TPL + ah];                 \
            const f32x4 m1 = MFMA(a0, Bw);                                     \
            const f32x4 m2 = MFMA(a1, Bw);                                     \
            const f32x4 qq = MFMA(a2, Bw);                                     \
            const f32x4 pt = MFMA(a3, Bw);                                     \
            _Pragma("unroll")                                                  \
            for (int r = 0; r < 4; ++r) {                                      \
                const float mu1 = m1[r], mu2 = m2[r];                          \
                const float ms  = fmaf(mu1, mu1, mu2 * mu2);                   \
                const float m12 = mu1 * mu2;                                   \
                const float s12 = pt[r] - m12;                                 \
                const float ssm = qq[r] - ms;                                  \
                const float num = fmaf(2.f, m12, C1) * fmaf(2.f, s12, C2);     \
                const float den = (ms + C1) * (ssm + C2);                      \
                sum += num * __builtin_amdgcn_rcpf(den);                       \
            }                                                                  \
        }                                                                      \
    }

    // ---- Prologue: stage tile 0 into A; drain; barrier also covers gw/TP init. ----
    STAGE(t0, stageA);
    LGKM0(); VMCNT0(); BAR();

    // Band matrix (both passes): B[n][k] = g[k - n - 3]  (validated R6-R14).
    half8 Bw;
    #pragma unroll
    for (int j = 0; j < 8; ++j)
        Bw[j] = gw[15 + hi * 8 + j - lo];

    // ---- Main loop: 2 tiles/iter, static ping-pong (NT even). ----
    #pragma unroll 1
    for (int i = 0; i < NT; i += 2) {
        STAGE(t0 + i + 1, stageB);           // async for next tile
        COMPUTE(stageA);
        VMCNT0(); BAR();                     // B fully staged; A free
        if (i + 2 < NT) STAGE(t0 + i + 2, stageA);
        COMPUTE(stageB);
        VMCNT0(); BAR();                     // A staged (or no-op last iter)
    }

    // ---- Per-wave reduce + one atomic per wave. ----
    #pragma unroll
    for (int off = 32; off > 0; off >>= 1) sum += __shfl_down(sum, off, 64);
    if (lane == 0)
        atomicAdd(&acc[(blockIdx.x * 4 + wv) & (NACC - 1)], sum);
#undef STAGE
#undef COMPUTE
}

__global__ void ssim_final(const float* __restrict__ acc, float* __restrict__ out) {
    float s = 0.f;
    #pragma unroll
    for (int i = 0; i < NACC; ++i) s += acc[i];
    out[0] = 0.1f * (1.0f - s / NPIX);
}

extern "C" void kernel_launch(void* const* d_in, const int* in_sizes, int n_in,
                              void* d_out, int out_size, void* d_ws, size_t ws_size,
                              hipStream_t stream) {
    const float* pred = (const float*)d_in[0];
    const float* targ = (const float*)d_in[1];
    const float* win  = (const float*)d_in[2];
    float* out = (float*)d_out;
    float* ws  = (float*)d_ws;

    // 512B: 64 accumulator slots + zero page (DMA source for OOB lanes).
    hipMemsetAsync(ws, 0, 512, stream);
    ssim_main<<<512, 256, 0, stream>>>(pred, targ, win, ws);
    ssim_final<<<1, 1, 0, stream>>>(ws, out);
}

// Round 17
// 43.750 us; speedup vs baseline: 2.2908x; 1.2223x over previous
//
#include <hip/hip_runtime.h>
#include <hip/hip_fp16.h>

typedef float f32x4 __attribute__((ext_vector_type(4)));

#define BH 8
#define ROWS 18            // BH + 10 halo rows
#define W 512
#define H 512
#define RST 548            // plane stride in half2 units (4 B each) — R5-proven layout
#define PLANE 4384         // half2 elements >= 7*548 + 528 (+slack)
#define NPIX (16.0f*3.0f*512.0f*512.0f)
#define NACC 64

// Block = 8 out rows x 512 cols, 512 threads (8 waves), ~17.6 KB LDS.
// Grid = 48 planes x 64 strips = 3072. Packed-fp16 VALU (2 MACs/instr):
// fields packed in half2 lanes: A=(mu1,mu2) chain, B=(q,x) chain.
__global__ __launch_bounds__(512) void ssim_main(const float* __restrict__ pred,
                                                 const float* __restrict__ targ,
                                                 const float* __restrict__ win,
                                                 float* __restrict__ acc) {
    const int tid = threadIdx.x;             // 0..511 = column

    // XCD swizzle (3072 % 8 == 0, bijective).
    const int b = (blockIdx.x & 7) * 384 + (blockIdx.x >> 3);
    const int strip = b & 63, nc = b >> 6;
    const int y0 = strip * BH;
    const float* Pb = pred + (size_t)nc * (W * H);
    const float* Tb = targ + (size_t)nc * (W * H);

    __shared__ __half2 plane[PLANE];         // 17536 B, reused for A then B round
    __shared__ float wsum[8];

    // Broadcast weights as half2(w,w): g from window row 5 / sqrt(center).
    const float inv = __builtin_amdgcn_rcpf(sqrtf(win[60]));
    __half2 g2[11];
    #pragma unroll
    for (int i = 0; i < 11; ++i) {
        const __half h = __float2half(win[55 + i] * inv);
        g2[i] = __halves2half2(h, h);
    }

    // Zero column pads once: pc 0..7 (cols -8..-1) and 520..527 (cols 512..519).
    // Field writes never touch them, so they survive both rounds.
    if (tid < 128) {
        const int r = tid >> 4, o = tid & 15;
        plane[r * RST + ((o < 8) ? o : (o + 512))] = __float2half2_rn(0.f);
    }

    // ---- Phase 1: vertical 11-tap conv, global -> packed registers. ----
    // Thread owns col tid; fully unrolled -> 36 independent VMEM loads.
    __half2 vA[BH], vB[BH];
    #pragma unroll
    for (int r = 0; r < BH; ++r) {
        vA[r] = __float2half2_rn(0.f);
        vB[r] = __float2half2_rn(0.f);
    }

    #pragma unroll
    for (int row = 0; row < ROWS; ++row) {
        const int iy = y0 - 5 + row;
        float p = 0.f, t = 0.f;
        if (iy >= 0 && iy < H) {             // block-uniform branch
            p = Pb[(size_t)iy * W + tid];
            t = Tb[(size_t)iy * W + tid];
        }
        const float q = fmaf(t, t, p * p);   // q = p^2 + t^2 (fp32, then quantize)
        const float x = p * t;
        const __half2 pt = __halves2half2(__float2half(p), __float2half(t));
        const __half2 qx = __halves2half2(__float2half(q), __float2half(x));
        #pragma unroll
        for (int r = 0; r < BH; ++r) {
            const int wi = row - r;          // compile-time per (row,r)
            if (wi >= 0 && wi <= 10) {
                vA[r] = __hfma2(g2[wi], pt, vA[r]);   // (mu1,mu2) += w*(p,t)
                vB[r] = __hfma2(g2[wi], qx, vB[r]);   // (q̄,x̄)  += w*(q,x)
            }
        }
    }

    // ---- Phase 2: horizontal 11-tap via LDS, 2 rounds (A then B plane). ----
    // Reader: out-row r2 = tid&7, 8-col segment s = tid>>3 (cols 8s..8s+7).
    // L[j] = plane[r2*RST + 8s + j]; px i tap k -> L[i+k+3] (pc = col+8).
    const int r2 = tid & 7, s = tid >> 3;
    const int rbase = r2 * RST + 8 * s;      // *4B: 16B-aligned (RST*4 % 16 == 0)

    __half2 hA[8];
    float sum = 0.f;
    const float C1 = 1e-4f, C2 = 9e-4f;

    // Round A: (mu1,mu2).
    #pragma unroll
    for (int r = 0; r < BH; ++r)
        plane[r * RST + 8 + tid] = vA[r];
    __syncthreads();
    {
        __half2 L[24];
        #pragma unroll
        for (int w = 0; w < 6; ++w)
            *(f32x4*)&L[4 * w] = *(const f32x4*)&plane[rbase + 4 * w];
        #pragma unroll
        for (int i = 0; i < 8; ++i) {
            __half2 hh = __hmul2(g2[0], L[i + 3]);
            #pragma unroll
            for (int k = 1; k < 11; ++k)
                hh = __hfma2(g2[k], L[i + 3 + k], hh);
            hA[i] = hh;
        }
    }
    __syncthreads();                         // A reads done before overwrite

    // Round B: (q̄,x̄) + fused SSIM epilogue.
    #pragma unroll
    for (int r = 0; r < BH; ++r)
        plane[r * RST + 8 + tid] = vB[r];
    __syncthreads();
    {
        __half2 L[24];
        #pragma unroll
        for (int w = 0; w < 6; ++w)
            *(f32x4*)&L[4 * w] = *(const f32x4*)&plane[rbase + 4 * w];
        #pragma unroll
        for (int i = 0; i < 8; ++i) {
            __half2 hh = __hmul2(g2[0], L[i + 3]);
            #pragma unroll
            for (int k = 1; k < 11; ++k)
                hh = __hfma2(g2[k], L[i + 3 + k], hh);
            const float mu1 = __half2float(__low2half(hA[i]));
            const float mu2 = __half2float(__high2half(hA[i]));
            const float qb  = __half2float(__low2half(hh));
            const float xb  = __half2float(__high2half(hh));
            const float ms  = fmaf(mu1, mu1, mu2 * mu2);   // mu1^2 + mu2^2
            const float m12 = mu1 * mu2;
            const float s12 = xb - m12;                    // sigma12
            const float ssm = qb - ms;                     // sigma1^2 + sigma2^2
            const float num = fmaf(2.f, m12, C1) * fmaf(2.f, s12, C2);
            const float den = (ms + C1) * (ssm + C2);
            sum += num * __builtin_amdgcn_rcpf(den);
        }
    }

    // ---- Reduce: wave -> block -> one atomic per block (64 slots). ----
    #pragma unroll
    for (int off = 32; off > 0; off >>= 1) sum += __shfl_down(sum, off, 64);
    const int wave = tid >> 6, lane = tid & 63;
    if (lane == 0) wsum[wave] = sum;
    __syncthreads();
    if (tid == 0) {
        float bs = 0.f;
        #pragma unroll
        for (int w = 0; w < 8; ++w) bs += wsum[w];
        atomicAdd(&acc[blockIdx.x & (NACC - 1)], bs);
    }
}

__global__ void ssim_final(const float* __restrict__ acc, float* __restrict__ out) {
    float s = 0.f;
    #pragma unroll
    for (int i = 0; i < NACC; ++i) s += acc[i];
    out[0] = 0.1f * (1.0f - s / NPIX);
}

extern "C" void kernel_launch(void* const* d_in, const int* in_sizes, int n_in,
                              void* d_out, int out_size, void* d_ws, size_t ws_size,
                              hipStream_t stream) {
    const float* pred = (const float*)d_in[0];
    const float* targ = (const float*)d_in[1];
    const float* win  = (const float*)d_in[2];
    float* out = (float*)d_out;
    float* acc = (float*)d_ws;

    hipMemsetAsync(acc, 0, NACC * sizeof(float), stream);  // fresh accumulators
    ssim_main<<<3072, 512, 0, stream>>>(pred, targ, win, acc);
    ssim_final<<<1, 1, 0, stream>>>(acc, out);
}

// Round 19
// 43.124 us; speedup vs baseline: 2.3240x; 1.0145x over previous
//
#include <hip/hip_runtime.h>
#include <hip/hip_fp16.h>

typedef float f32x4 __attribute__((ext_vector_type(4)));
typedef __fp16 fp16v2 __attribute__((ext_vector_type(2)));

#define BH 8
#define ROWS 18            // BH + 10 halo rows
#define W 512
#define H 512
#define RST 548            // plane stride in half2 units (4 B each) — R5/R17-proven
#define PLANE 4384         // half2 elements >= 7*548 + 528 (+slack)
#define NPIX (16.0f*3.0f*512.0f*512.0f)
#define NACC 64

static __device__ __forceinline__ __half2 pkrtz(float a, float b) {
    fp16v2 r = __builtin_amdgcn_cvt_pkrtz(a, b);   // 1 instr: v_cvt_pkrtz_f16_f32
    return *(__half2*)&r;
}

// Block = 8 out rows x 512 cols, 256 threads (4 waves), 2 cols/thread.
// ~17.6 KB LDS -> 8 blocks/CU cap. Grid = 48 planes x 64 strips = 3072.
// Packed-fp16 VALU: field pairs (mu1,mu2) / (q,x) in half2 lanes.
__global__ __launch_bounds__(256) void ssim_main(const float* __restrict__ pred,
                                                 const float* __restrict__ targ,
                                                 const float* __restrict__ win,
                                                 float* __restrict__ acc) {
    const int tid = threadIdx.x;             // owns cols 2tid, 2tid+1

    // XCD swizzle (3072 % 8 == 0, bijective).
    const int b = (blockIdx.x & 7) * 384 + (blockIdx.x >> 3);
    const int strip = b & 63, nc = b >> 6;
    const int y0 = strip * BH;
    const float* Pb = pred + (size_t)nc * (W * H);
    const float* Tb = targ + (size_t)nc * (W * H);

    __shared__ __half2 plane[PLANE];         // 17536 B, reused A then B round
    __shared__ float wsum[4];

    // Broadcast weights as half2(w,w).
    const float inv = __builtin_amdgcn_rcpf(sqrtf(win[60]));
    __half2 g2[11];
    #pragma unroll
    for (int i = 0; i < 11; ++i) {
        const float v = win[55 + i] * inv;
        g2[i] = pkrtz(v, v);
    }

    // Zero column pads once (pc 0..7 and 520..527 per row); survive both rounds.
    if (tid < 128) {
        const int r = tid >> 4, o = tid & 15;
        plane[r * RST + ((o < 8) ? o : (o + 512))] = pkrtz(0.f, 0.f);
    }

    // ---- Phase 1: vertical 11-tap conv, global -> packed registers. ----
    __half2 vA0[BH], vB0[BH], vA1[BH], vB1[BH];
    #pragma unroll
    for (int r = 0; r < BH; ++r) {
        vA0[r] = pkrtz(0.f, 0.f); vB0[r] = pkrtz(0.f, 0.f);
        vA1[r] = pkrtz(0.f, 0.f); vB1[r] = pkrtz(0.f, 0.f);
    }

    const int c0 = 2 * tid;
    #pragma unroll
    for (int row = 0; row < ROWS; ++row) {
        const int iy = y0 - 5 + row;
        float2 pv = make_float2(0.f, 0.f), tv = make_float2(0.f, 0.f);
        if (iy >= 0 && iy < H) {             // block-uniform branch
            pv = *(const float2*)(Pb + (size_t)iy * W + c0);
            tv = *(const float2*)(Tb + (size_t)iy * W + c0);
        }
        const float q0 = fmaf(tv.x, tv.x, pv.x * pv.x);
        const float q1 = fmaf(tv.y, tv.y, pv.y * pv.y);
        const float x0 = pv.x * tv.x, x1 = pv.y * tv.y;
        const __half2 pt0 = pkrtz(pv.x, tv.x), qx0 = pkrtz(q0, x0);
        const __half2 pt1 = pkrtz(pv.y, tv.y), qx1 = pkrtz(q1, x1);
        #pragma unroll
        for (int r = 0; r < BH; ++r) {
            const int wi = row - r;          // compile-time per (row,r)
            if (wi >= 0 && wi <= 10) {
                vA0[r] = __hfma2(g2[wi], pt0, vA0[r]);  // (mu1,mu2) col c0
                vB0[r] = __hfma2(g2[wi], qx0, vB0[r]);  // (q̄,x̄)  col c0
                vA1[r] = __hfma2(g2[wi], pt1, vA1[r]);  // col c0+1
                vB1[r] = __hfma2(g2[wi], qx1, vB1[r]);
            }
        }
    }

    // ---- Phase 2: horizontal 11-tap via LDS, 2 rounds. ----
    // Reader: out-row r2 = tid&7, 16-col segment s = tid>>3 (cols 16s..16s+15).
    // L[j] = plane[r2*RST + 16s + j]; px i tap k -> L[i+k+3].
    const int r2 = tid & 7, s = tid >> 3;
    const int rbase = r2 * RST + 16 * s;     // 16B-aligned (548*4 % 16 == 0)

    __half2 hA[16];
    float sum = 0.f;
    const float C1 = 1e-4f, C2 = 9e-4f;

    // Round A: (mu1,mu2). Merged 8B writes (pc = 8+c0 even -> aligned).
    #pragma unroll
    for (int r = 0; r < BH; ++r) {
        const int wb = r * RST + 8 + c0;
        plane[wb]     = vA0[r];
        plane[wb + 1] = vA1[r];
    }
    __syncthreads();
    {
        __half2 L[32];
        #pragma unroll
        for (int w = 0; w < 8; ++w)
            *(f32x4*)&L[4 * w] = *(const f32x4*)&plane[rbase + 4 * w];
        #pragma unroll
        for (int i = 0; i < 16; ++i) {
            __half2 hh = __hmul2(g2[0], L[i + 3]);
            #pragma unroll
            for (int k = 1; k < 11; ++k)
                hh = __hfma2(g2[k], L[i + 3 + k], hh);
            hA[i] = hh;
        }
    }
    __syncthreads();                         // A reads done before overwrite

    // Round B: (q̄,x̄) + fused fp32 epilogue.
    #pragma unroll
    for (int r = 0; r < BH; ++r) {
        const int wb = r * RST + 8 + c0;
        plane[wb]     = vB0[r];
        plane[wb + 1] = vB1[r];
    }
    __syncthreads();
    {
        __half2 L[32];
        #pragma unroll
        for (int w = 0; w < 8; ++w)
            *(f32x4*)&L[4 * w] = *(const f32x4*)&plane[rbase + 4 * w];
        #pragma unroll
        for (int i = 0; i < 16; ++i) {
            __half2 hh = __hmul2(g2[0], L[i + 3]);
            #pragma unroll
            for (int k = 1; k < 11; ++k)
                hh = __hfma2(g2[k], L[i + 3 + k], hh);
            const float mu1 = __half2float(__low2half(hA[i]));
            const float mu2 = __half2float(__high2half(hA[i]));
            const float qb  = __half2float(__low2half(hh));
            const float xb  = __half2float(__high2half(hh));
            const float ms  = fmaf(mu1, mu1, mu2 * mu2);   // mu1^2 + mu2^2
            const float m12 = mu1 * mu2;
            const float s12 = xb - m12;                    // sigma12
            const float ssm = qb - ms;                     // sigma1^2 + sigma2^2
            const float num = fmaf(2.f, m12, C1) * fmaf(2.f, s12, C2);
            const float den = (ms + C1) * (ssm + C2);
            sum += num * __builtin_amdgcn_rcpf(den);
        }
    }

    // ---- Reduce: wave -> block -> one atomic per block (64 slots). ----
    #pragma unroll
    for (int off = 32; off > 0; off >>= 1) sum += __shfl_down(sum, off, 64);
    const int wave = tid >> 6, lane = tid & 63;
    if (lane == 0) wsum[wave] = sum;
    __syncthreads();
    if (tid == 0) {
        atomicAdd(&acc[blockIdx.x & (NACC - 1)],
                  wsum[0] + wsum[1] + wsum[2] + wsum[3]);
    }
}

__global__ void ssim_final(const float* __restrict__ acc, float* __restrict__ out) {
    float s = 0.f;
    #pragma unroll
    for (int i = 0; i < NACC; ++i) s += acc[i];
    out[0] = 0.1f * (1.0f - s / NPIX);
}

extern "C" void kernel_launch(void* const* d_in, const int* in_sizes, int n_in,
                              void* d_out, int out_size, void* d_ws, size_t ws_size,
                              hipStream_t stream) {
    const float* pred = (const float*)d_in[0];
    const float* targ = (const float*)d_in[1];
    const float* win  = (const float*)d_in[2];
    float* out = (float*)d_out;
    float* acc = (float*)d_ws;

    (void)hipMemsetAsync(acc, 0, NACC * sizeof(float), stream);  // fresh accumulators
    ssim_main<<<3072, 256, 0, stream>>>(pred, targ, win, acc);
    ssim_final<<<1, 1, 0, stream>>>(acc, out);
}